// Round 6
// baseline (422.999 us; speedup 1.0000x reference)
//
#include <hip/hip_runtime.h>
#include <cstdint>
#include <cstddef>
#include <math.h>

typedef _Float16 f16;
typedef _Float16 f16x8 __attribute__((ext_vector_type(8)));
typedef _Float16 f16x4 __attribute__((ext_vector_type(4)));
typedef float f32x4 __attribute__((ext_vector_type(4)));
typedef float f32x16 __attribute__((ext_vector_type(16)));

#define MFMA16(A, B, C) __builtin_amdgcn_mfma_f32_16x16x32_f16((A), (B), (C), 0, 0, 0)
#define MFMA32(A, B, C) __builtin_amdgcn_mfma_f32_32x32x16_f16((A), (B), (C), 0, 0, 0)

#if __has_builtin(__builtin_amdgcn_exp2f)
#define EXP2(x) __builtin_amdgcn_exp2f(x)
#else
#define EXP2(x) exp2f(x)
#endif

#define NBLK 768

__device__ __forceinline__ f16x8 ld8(const f16* p) { return *(const f16x8*)p; }
__device__ __forceinline__ void st8(f16* p, f16x8 v) { *(f16x8*)p = v; }
__device__ __forceinline__ void st4(f16* p, f16x4 v) { *(f16x4*)p = v; }

__device__ __forceinline__ void gll16(const f16* g, f16* l) {
    __builtin_amdgcn_global_load_lds(
        (__attribute__((address_space(1))) void*)(uintptr_t)g,
        (__attribute__((address_space(3))) void*)(unsigned)(uintptr_t)l,
        16, 0, 0);
}

// Grid barrier, poison-tolerant: flags start as 0xAAAAAAAA (negative signed)
// or 0; blocks publish monotonically increasing phase numbers; waiters check
// flag >= phase. Device-scope atomics + threadfence for cross-XCD coherence.
__device__ __forceinline__ void gridbarrier(int* flags, int phase) {
    __syncthreads();
    if (threadIdx.x == 0) {
        __threadfence();   // release: our global writes visible device-wide
        __hip_atomic_store(&flags[blockIdx.x], phase, __ATOMIC_RELEASE,
                           __HIP_MEMORY_SCOPE_AGENT);
    }
    if (threadIdx.x < 64) {
        for (;;) {
            int ok = 1;
            #pragma unroll
            for (int i = 0; i < NBLK / 64; ++i) {
                int v = __hip_atomic_load(&flags[threadIdx.x + i * 64],
                                          __ATOMIC_RELAXED, __HIP_MEMORY_SCOPE_AGENT);
                ok &= (v >= phase);
            }
            if (__all(ok)) break;
            __builtin_amdgcn_s_sleep(4);
        }
    }
    __syncthreads();
    __threadfence();       // acquire: invalidate caches before reading others' data
}

// ws f16 layout (elements):
//   Qc 0, Kc 2097152, Vc 4194304, Wqc 6291456, Wkc 7340032, Wvc 8388608,
//   Woc 9437184, qlin 10485760, klin 12582912, vT 14680064, merged 16777216,
//   flags (int) at f16 idx 18874368
#define QSCALE 0.04508422002778009f   // log2(e)/32, folded into qlin

__global__ __launch_bounds__(256, 3) void fused(
    const float* __restrict__ Q, const float* __restrict__ K, const float* __restrict__ V,
    const float* __restrict__ Wq, const float* __restrict__ bq,
    const float* __restrict__ Wk, const float* __restrict__ bk,
    const float* __restrict__ Wv, const float* __restrict__ bv,
    const float* __restrict__ Wo, const float* __restrict__ bo,
    f16* __restrict__ ws, float* __restrict__ out)
{
    __shared__ union {
        struct { f16 As[2 * 4096]; f16 Bs[2 * 8192]; } g;                 // 48 KB
        struct { f16 Ks[2][2048]; f16 Vs[2][2176]; f16 Ps[4][1280]; } a;  // 26.5 KB
        struct { f16 As[2 * 4096]; f16 Bs[2 * 4096]; } o;                 // 32 KB
    } sm;

    int* flags = (int*)(ws + 18874368);
    const int t = threadIdx.x;
    const int w = t >> 6, lane = t & 63, lg = lane >> 4, ll = lane & 15;

    if (t == 0)
        __hip_atomic_store(&flags[blockIdx.x], 0, __ATOMIC_RELAXED,
                           __HIP_MEMORY_SCOPE_AGENT);

    // ========== P0: fp32 -> f16 cast, 7 sweeps, 10485760 elements total ======
    {
        f16* dst = ws;
        #pragma unroll
        for (int sweep = 0; sweep < 7; ++sweep) {
            size_t e = ((size_t)sweep * NBLK * 256 + (size_t)blockIdx.x * 256 + t) * 8;
            if (e < 10485760) {
                const float* s; size_t r;
                if (e < 2097152)      { s = Q;  r = e; }
                else if (e < 4194304) { s = K;  r = e - 2097152; }
                else if (e < 6291456) { s = V;  r = e - 4194304; }
                else if (e < 7340032) { s = Wq; r = e - 6291456; }
                else if (e < 8388608) { s = Wk; r = e - 7340032; }
                else if (e < 9437184) { s = Wv; r = e - 8388608; }
                else                  { s = Wo; r = e - 9437184; }
                float4 a = *(const float4*)(s + r);
                float4 b = *(const float4*)(s + r + 4);
                f16x8 o;
                o[0]=(f16)a.x; o[1]=(f16)a.y; o[2]=(f16)a.z; o[3]=(f16)a.w;
                o[4]=(f16)b.x; o[5]=(f16)b.y; o[6]=(f16)b.z; o[7]=(f16)b.w;
                st8(dst + e, o);
            }
        }
    }
    gridbarrier(flags, 1);

    // ================= P1: fused QKV GEMM, 64x128 tile, BK=64, dbuf ==========
    {
        const int v = blockIdx.x;
        const int bx = v % 24, bm = v / 24;
        const int mat = bx >> 3, bn = bx & 7;
        const f16* A  = ws + (size_t)mat * 2097152;
        const f16* Bw = ws + 6291456 + (size_t)mat * 1048576;
        const float* bias = (mat == 0) ? bq : (mat == 1) ? bk : bv;
        f16* C = ws + 10485760 + (size_t)mat * 2097152;

        f16* As = sm.g.As;
        f16* Bs = sm.g.Bs;
        const int swz = ((lane & 7) ^ (lane >> 3)) * 8;   // swizzled source col

        const f16* Ap = A  + (size_t)(bm * 64  + w * 8 + (lane >> 3)) * 1024 + swz;
        const f16* Bp = Bw + (size_t)(bn * 128 + w * 8 + (lane >> 3)) * 1024 + swz;

        f32x4 acc[4][2] = {};
        const int ll7 = ll & 7;

        gll16(Ap,         &As[w * 512]);
        gll16(Ap + 32768, &As[2048 + w * 512]);
        #pragma unroll
        for (int q = 0; q < 4; ++q)
            gll16(Bp + q * 32768, &Bs[q * 2048 + w * 512]);

        #pragma unroll 2
        for (int kt = 0; kt < 16; ++kt) {
            const int cur = kt & 1;
            __syncthreads();
            if (kt < 15) {
                const f16* Ak = Ap + (kt + 1) * 64;
                const f16* Bk = Bp + (kt + 1) * 64;
                f16* Ad = &As[(cur ^ 1) * 4096 + w * 512];
                f16* Bd = &Bs[(cur ^ 1) * 8192 + w * 512];
                gll16(Ak,         Ad);
                gll16(Ak + 32768, Ad + 2048);
                #pragma unroll
                for (int q = 0; q < 4; ++q)
                    gll16(Bk + q * 32768, Bd + q * 2048);
            }
            const f16* Ac = &As[cur * 4096];
            const f16* Bc = &Bs[cur * 8192];
            #pragma unroll
            for (int ks = 0; ks < 2; ++ks) {
                f16x8 af[4], bf[2];
                #pragma unroll
                for (int i = 0; i < 4; ++i)
                    af[i] = ld8(&Ac[(i * 16 + ll) * 64 + (((ks * 4 + lg) ^ ll7) * 8)]);
                #pragma unroll
                for (int j = 0; j < 2; ++j)
                    bf[j] = ld8(&Bc[(w * 32 + j * 16 + ll) * 64 + (((ks * 4 + lg) ^ ll7) * 8)]);
                #pragma unroll
                for (int i = 0; i < 4; ++i)
                    #pragma unroll
                    for (int j = 0; j < 2; ++j)
                        acc[i][j] = MFMA16(af[i], bf[j], acc[i][j]);
            }
        }

        #pragma unroll
        for (int j = 0; j < 2; ++j) {
            const int n = bn * 128 + w * 32 + j * 16 + ll;
            const float bv_ = bias[n];
            if (mat == 0) {
                #pragma unroll
                for (int i = 0; i < 4; ++i) {
                    const int m0 = bm * 64 + i * 16 + lg * 4;
                    #pragma unroll
                    for (int r = 0; r < 4; ++r)
                        C[(size_t)(m0 + r) * 1024 + n] = (f16)((acc[i][j][r] + bv_) * QSCALE);
                }
            } else if (mat == 1) {
                #pragma unroll
                for (int i = 0; i < 4; ++i) {
                    const int m0 = bm * 64 + i * 16 + lg * 4;
                    #pragma unroll
                    for (int r = 0; r < 4; ++r)
                        C[(size_t)(m0 + r) * 1024 + n] = (f16)(acc[i][j][r] + bv_);
                }
            } else {
                // vT[((bb*64 + h)*16 + e)*1024 + s], h = n>>4, e = n&15
                #pragma unroll
                for (int i = 0; i < 4; ++i) {
                    const int m0 = bm * 64 + i * 16 + lg * 4;
                    const int bb = m0 >> 10, s0 = m0 & 1023;
                    f16x4 pv;
                    pv[0] = (f16)(acc[i][j][0] + bv_);
                    pv[1] = (f16)(acc[i][j][1] + bv_);
                    pv[2] = (f16)(acc[i][j][2] + bv_);
                    pv[3] = (f16)(acc[i][j][3] + bv_);
                    st4(C + ((size_t)((bb * 64 + (n >> 4)) * 16 + (n & 15))) * 1024 + s0, pv);
                }
            }
        }
    }
    gridbarrier(flags, 2);

    // ================= P2: flash attention (1024 tiles over 768 blocks) ======
    {
        const f16* qlin = ws + 10485760;
        const f16* klin = ws + 12582912;
        const f16* vT   = ws + 14680064;
        f16* merged     = ws + 16777216;

        const int l5 = lane & 31, hh = lane >> 5;
        int offKa[4];
        #pragma unroll
        for (int mt = 0; mt < 4; ++mt) {
            const int r = mt * 32 + l5, g = r >> 2;
            offKa[mt] = g * 64 + (((((r & 3) * 2 + hh) + g) & 7) * 8);
        }
        const int sp = ((lane & 7) - (lane >> 3)) & 7;

        for (int v = blockIdx.x; v < 1024; v += NBLK) {
            __syncthreads();   // protect shared tile reuse across v-iterations
            const int h = v & 63, qt = (v >> 6) & 7, b = v >> 9;
            const int rowQ0 = b * 1024 + qt * 128;
            const int colh = h * 16;

            f16x8 qf = ld8(qlin + (size_t)(rowQ0 + w * 32 + l5) * 1024 + colh + hh * 8);

            const f16* kptr = klin + (size_t)(b * 1024 + w * 32 + (lane >> 3) * 4 + (sp >> 1)) * 1024
                              + colh + (sp & 1) * 8;
            const int ve = t >> 4, vk = (t & 15) * 8;
            const f16* vptr = vT + (size_t)((b * 64 + h) * 16 + ve) * 1024 + vk;
            f16* vdst0 = &sm.a.Vs[0][ve * 136 + vk];
            f16* vdst1 = &sm.a.Vs[1][ve * 136 + vk];

            float lsum = 0.f;
            f32x4 O0 = {}, O1 = {};
            f16* Pw = sm.a.Ps[w];

            f16x8 vv = ld8(vptr);
            gll16(kptr, &sm.a.Ks[0][w * 512]);
            st8(vdst0, vv);

            for (int kt = 0; kt < 8; ++kt) {
                const int cur = kt & 1;
                if (kt < 7) vv = ld8(vptr + (kt + 1) * 128);
                __syncthreads();
                if (kt < 7) {
                    gll16(kptr + (size_t)(kt + 1) * 131072, &sm.a.Ks[cur ^ 1][w * 512]);
                    st8(cur ? vdst0 : vdst1, vv);
                }

                #pragma unroll
                for (int mt = 0; mt < 4; ++mt) {
                    f16x8 ka = ld8(&sm.a.Ks[cur][offKa[mt]]);
                    f32x16 Sz = {};
                    f32x16 S = MFMA32(ka, qf, Sz);   // S^T[key][q], q = l5

                    #pragma unroll
                    for (int g = 0; g < 4; ++g) {
                        float p0 = EXP2(S[4 * g + 0]);
                        float p1 = EXP2(S[4 * g + 1]);
                        float p2 = EXP2(S[4 * g + 2]);
                        float p3 = EXP2(S[4 * g + 3]);
                        lsum += (p0 + p1) + (p2 + p3);
                        f16x4 pk;
                        pk[0] = (f16)p0; pk[1] = (f16)p1; pk[2] = (f16)p2; pk[3] = (f16)p3;
                        st4(&Pw[l5 * 40 + g * 8 + hh * 4], pk);
                    }

                    f16x8 va  = ld8(&sm.a.Vs[cur][ll * 136 + mt * 32 + lg * 8]);
                    f16x8 pb0 = ld8(&Pw[ll * 40 + lg * 8]);
                    f16x8 pb1 = ld8(&Pw[(16 + ll) * 40 + lg * 8]);
                    O0 = MFMA16(va, pb0, O0);
                    O1 = MFMA16(va, pb1, O1);
                }
            }

            lsum += __shfl_xor(lsum, 32);
            const float i0 = 1.f / __shfl(lsum, ll);
            const float i1 = 1.f / __shfl(lsum, 16 + ll);

            f16x4 o0, o1;
            o0[0]=(f16)(O0[0]*i0); o0[1]=(f16)(O0[1]*i0); o0[2]=(f16)(O0[2]*i0); o0[3]=(f16)(O0[3]*i0);
            o1[0]=(f16)(O1[0]*i1); o1[1]=(f16)(O1[1]*i1); o1[2]=(f16)(O1[2]*i1); o1[3]=(f16)(O1[3]*i1);
            const size_t q0 = rowQ0 + w * 32 + ll;
            st4(merged + q0 * 1024 + colh + lg * 4, o0);
            st4(merged + (q0 + 16) * 1024 + colh + lg * 4, o1);
        }
    }
    gridbarrier(flags, 3);

    // ================= P3: output projection, 64x64 tile, dbuf, fp32 out =====
    if (blockIdx.x < 512) {
        const f16* Am  = ws + 16777216;
        const f16* Bw  = ws + 9437184;
        const int bn = blockIdx.x & 15, bm = blockIdx.x >> 4;

        f16* As = sm.o.As;
        f16* Bs = sm.o.Bs;
        const int swz = ((lane & 7) ^ (lane >> 3)) * 8;

        const f16* Ap = Am + (size_t)(bm * 64 + w * 8 + (lane >> 3)) * 1024 + swz;
        const f16* Bp = Bw + (size_t)(bn * 64 + w * 8 + (lane >> 3)) * 1024 + swz;

        f32x4 acc[4] = {};
        const int ll7 = ll & 7;

        gll16(Ap,         &As[w * 512]);
        gll16(Ap + 32768, &As[2048 + w * 512]);
        gll16(Bp,         &Bs[w * 512]);
        gll16(Bp + 32768, &Bs[2048 + w * 512]);

        #pragma unroll 2
        for (int kt = 0; kt < 16; ++kt) {
            const int cur = kt & 1;
            __syncthreads();
            if (kt < 15) {
                const f16* Ak = Ap + (kt + 1) * 64;
                const f16* Bk = Bp + (kt + 1) * 64;
                f16* Ad = &As[(cur ^ 1) * 4096 + w * 512];
                f16* Bd = &Bs[(cur ^ 1) * 4096 + w * 512];
                gll16(Ak,         Ad);
                gll16(Ak + 32768, Ad + 2048);
                gll16(Bk,         Bd);
                gll16(Bk + 32768, Bd + 2048);
            }
            const f16* Ac = &As[cur * 4096];
            const f16* Bc = &Bs[cur * 4096];
            #pragma unroll
            for (int ks = 0; ks < 2; ++ks) {
                f16x8 af[4], bf;
                #pragma unroll
                for (int i = 0; i < 4; ++i)
                    af[i] = ld8(&Ac[(i * 16 + ll) * 64 + (((ks * 4 + lg) ^ ll7) * 8)]);
                bf = ld8(&Bc[(w * 16 + ll) * 64 + (((ks * 4 + lg) ^ ll7) * 8)]);
                #pragma unroll
                for (int i = 0; i < 4; ++i)
                    acc[i] = MFMA16(af[i], bf, acc[i]);
            }
        }

        const int n = bn * 64 + w * 16 + ll;
        const float bv_ = bo[n];
        #pragma unroll
        for (int i = 0; i < 4; ++i) {
            const int m0 = bm * 64 + i * 16 + lg * 4;
            #pragma unroll
            for (int r = 0; r < 4; ++r)
                out[(size_t)(m0 + r) * 1024 + n] = acc[i][r] + bv_;
        }
    }
}

extern "C" void kernel_launch(void* const* d_in, const int* in_sizes, int n_in,
                              void* d_out, int out_size, void* d_ws, size_t ws_size,
                              hipStream_t stream) {
    (void)in_sizes; (void)n_in; (void)out_size; (void)ws_size;
    const float* Q  = (const float*)d_in[0];
    const float* K  = (const float*)d_in[1];
    const float* V  = (const float*)d_in[2];
    const float* Wq = (const float*)d_in[3];
    const float* bq = (const float*)d_in[4];
    const float* Wk = (const float*)d_in[5];
    const float* bk = (const float*)d_in[6];
    const float* Wv = (const float*)d_in[7];
    const float* bv = (const float*)d_in[8];
    const float* Wo = (const float*)d_in[9];
    const float* bo = (const float*)d_in[10];
    float* out = (float*)d_out;
    f16* ws = (f16*)d_ws;

    fused<<<NBLK, 256, 0, stream>>>(Q, K, V, Wq, bq, Wk, bk, Wv, bv, Wo, bo, ws, out);
}

// Round 7
// 396.186 us; speedup vs baseline: 1.0677x; 1.0677x over previous
//
#include <hip/hip_runtime.h>
#include <cstdint>
#include <cstddef>
#include <math.h>

typedef _Float16 f16;
typedef _Float16 f16x8 __attribute__((ext_vector_type(8)));
typedef _Float16 f16x4 __attribute__((ext_vector_type(4)));
typedef float f32x4 __attribute__((ext_vector_type(4)));
typedef float f32x16 __attribute__((ext_vector_type(16)));

#define MFMA16(A, B, C) __builtin_amdgcn_mfma_f32_16x16x32_f16((A), (B), (C), 0, 0, 0)
#define MFMA32(A, B, C) __builtin_amdgcn_mfma_f32_32x32x16_f16((A), (B), (C), 0, 0, 0)

#if __has_builtin(__builtin_amdgcn_exp2f)
#define EXP2(x) __builtin_amdgcn_exp2f(x)
#else
#define EXP2(x) exp2f(x)
#endif

#define NBLK 768

__device__ __forceinline__ f16x8 ld8(const f16* p) { return *(const f16x8*)p; }
__device__ __forceinline__ void st8(f16* p, f16x8 v) { *(f16x8*)p = v; }
__device__ __forceinline__ void st4(f16* p, f16x4 v) { *(f16x4*)p = v; }

__device__ __forceinline__ void gll16(const f16* g, f16* l) {
    __builtin_amdgcn_global_load_lds(
        (__attribute__((address_space(1))) void*)(uintptr_t)g,
        (__attribute__((address_space(3))) void*)(unsigned)(uintptr_t)l,
        16, 0, 0);
}

// Two-level grid barrier, poison-tolerant (flags/gen start 0xAAAAAAAA < 1).
// Arrive: each block release-stores phase into its OWN slot (no RMW, no init).
// Aggregate: block 0 polls all 768 flags (256 thr x 3 coalesced loads/round),
// then publishes a single generation word. Wait: other blocks poll ONE lane,
// ONE cacheline. Poll traffic ~KB/round vs the old design's ~590 KB/round at
// 10x the rate (~6 TB/s of fabric congestion -- the round-6 killer).
__device__ __forceinline__ void gridbarrier(int* flags, int* gen, int phase) {
    __syncthreads();
    if (threadIdx.x == 0) {
        __threadfence();   // release: our global writes visible device-wide
        __hip_atomic_store(&flags[blockIdx.x], phase, __ATOMIC_RELEASE,
                           __HIP_MEMORY_SCOPE_AGENT);
    }
    if (blockIdx.x == 0) {
        for (;;) {
            int ok = 1;
            #pragma unroll
            for (int i = 0; i < NBLK / 256; ++i) {
                int v = __hip_atomic_load(&flags[threadIdx.x + i * 256],
                                          __ATOMIC_RELAXED, __HIP_MEMORY_SCOPE_AGENT);
                ok &= (v >= phase);
            }
            if (__syncthreads_and(ok)) break;
            __builtin_amdgcn_s_sleep(8);
        }
        if (threadIdx.x == 0) {
            __threadfence();
            __hip_atomic_store(gen, phase, __ATOMIC_RELEASE,
                               __HIP_MEMORY_SCOPE_AGENT);
        }
    } else {
        if (threadIdx.x == 0) {
            while (__hip_atomic_load(gen, __ATOMIC_RELAXED,
                                     __HIP_MEMORY_SCOPE_AGENT) < phase)
                __builtin_amdgcn_s_sleep(8);
        }
        __syncthreads();
    }
    __threadfence();       // acquire: discard stale cached data before reading
}

// ws f16 layout (elements):
//   Qc 0, Kc 2097152, Vc 4194304, Wqc 6291456, Wkc 7340032, Wvc 8388608,
//   Woc 9437184, qlin 10485760, klin 12582912, vT 14680064, merged 16777216,
//   flags (int[768]) at f16 idx 18874368, gen (int) at flags[768]
#define QSCALE 0.04508422002778009f   // log2(e)/32, folded into qlin

__global__ __launch_bounds__(256, 3) void fused(
    const float* __restrict__ Q, const float* __restrict__ K, const float* __restrict__ V,
    const float* __restrict__ Wq, const float* __restrict__ bq,
    const float* __restrict__ Wk, const float* __restrict__ bk,
    const float* __restrict__ Wv, const float* __restrict__ bv,
    const float* __restrict__ Wo, const float* __restrict__ bo,
    f16* __restrict__ ws, float* __restrict__ out)
{
    __shared__ union {
        struct { f16 As[2 * 4096]; f16 Bs[2 * 8192]; } g;                 // 48 KB
        struct { f16 Ks[2][2048]; f16 Vs[2][2176]; f16 Ps[4][1280]; } a;  // 26.5 KB
        struct { f16 As[2 * 4096]; f16 Bs[2 * 4096]; } o;                 // 32 KB
    } sm;

    int* flags = (int*)(ws + 18874368);
    int* gen   = flags + NBLK;
    const int t = threadIdx.x;
    const int w = t >> 6, lane = t & 63, lg = lane >> 4, ll = lane & 15;

    // ========== P0: fp32 -> f16 cast, 7 sweeps, 10485760 elements total ======
    {
        f16* dst = ws;
        #pragma unroll
        for (int sweep = 0; sweep < 7; ++sweep) {
            size_t e = ((size_t)sweep * NBLK * 256 + (size_t)blockIdx.x * 256 + t) * 8;
            if (e < 10485760) {
                const float* s; size_t r;
                if (e < 2097152)      { s = Q;  r = e; }
                else if (e < 4194304) { s = K;  r = e - 2097152; }
                else if (e < 6291456) { s = V;  r = e - 4194304; }
                else if (e < 7340032) { s = Wq; r = e - 6291456; }
                else if (e < 8388608) { s = Wk; r = e - 7340032; }
                else if (e < 9437184) { s = Wv; r = e - 8388608; }
                else                  { s = Wo; r = e - 9437184; }
                float4 a = *(const float4*)(s + r);
                float4 b = *(const float4*)(s + r + 4);
                f16x8 o;
                o[0]=(f16)a.x; o[1]=(f16)a.y; o[2]=(f16)a.z; o[3]=(f16)a.w;
                o[4]=(f16)b.x; o[5]=(f16)b.y; o[6]=(f16)b.z; o[7]=(f16)b.w;
                st8(dst + e, o);
            }
        }
    }
    gridbarrier(flags, gen, 1);

    // ================= P1: fused QKV GEMM, 64x128 tile, BK=64, dbuf ==========
    {
        const int v = blockIdx.x;
        const int bx = v % 24, bm = v / 24;
        const int mat = bx >> 3, bn = bx & 7;
        const f16* A  = ws + (size_t)mat * 2097152;
        const f16* Bw = ws + 6291456 + (size_t)mat * 1048576;
        const float* bias = (mat == 0) ? bq : (mat == 1) ? bk : bv;
        f16* C = ws + 10485760 + (size_t)mat * 2097152;

        f16* As = sm.g.As;
        f16* Bs = sm.g.Bs;
        const int swz = ((lane & 7) ^ (lane >> 3)) * 8;   // swizzled source col

        const f16* Ap = A  + (size_t)(bm * 64  + w * 8 + (lane >> 3)) * 1024 + swz;
        const f16* Bp = Bw + (size_t)(bn * 128 + w * 8 + (lane >> 3)) * 1024 + swz;

        f32x4 acc[4][2] = {};
        const int ll7 = ll & 7;

        gll16(Ap,         &As[w * 512]);
        gll16(Ap + 32768, &As[2048 + w * 512]);
        #pragma unroll
        for (int q = 0; q < 4; ++q)
            gll16(Bp + q * 32768, &Bs[q * 2048 + w * 512]);

        #pragma unroll 2
        for (int kt = 0; kt < 16; ++kt) {
            const int cur = kt & 1;
            __syncthreads();
            if (kt < 15) {
                const f16* Ak = Ap + (kt + 1) * 64;
                const f16* Bk = Bp + (kt + 1) * 64;
                f16* Ad = &As[(cur ^ 1) * 4096 + w * 512];
                f16* Bd = &Bs[(cur ^ 1) * 8192 + w * 512];
                gll16(Ak,         Ad);
                gll16(Ak + 32768, Ad + 2048);
                #pragma unroll
                for (int q = 0; q < 4; ++q)
                    gll16(Bk + q * 32768, Bd + q * 2048);
            }
            const f16* Ac = &As[cur * 4096];
            const f16* Bc = &Bs[cur * 8192];
            #pragma unroll
            for (int ks = 0; ks < 2; ++ks) {
                f16x8 af[4], bf[2];
                #pragma unroll
                for (int i = 0; i < 4; ++i)
                    af[i] = ld8(&Ac[(i * 16 + ll) * 64 + (((ks * 4 + lg) ^ ll7) * 8)]);
                #pragma unroll
                for (int j = 0; j < 2; ++j)
                    bf[j] = ld8(&Bc[(w * 32 + j * 16 + ll) * 64 + (((ks * 4 + lg) ^ ll7) * 8)]);
                #pragma unroll
                for (int i = 0; i < 4; ++i)
                    #pragma unroll
                    for (int j = 0; j < 2; ++j)
                        acc[i][j] = MFMA16(af[i], bf[j], acc[i][j]);
            }
        }

        #pragma unroll
        for (int j = 0; j < 2; ++j) {
            const int n = bn * 128 + w * 32 + j * 16 + ll;
            const float bv_ = bias[n];
            if (mat == 0) {
                #pragma unroll
                for (int i = 0; i < 4; ++i) {
                    const int m0 = bm * 64 + i * 16 + lg * 4;
                    #pragma unroll
                    for (int r = 0; r < 4; ++r)
                        C[(size_t)(m0 + r) * 1024 + n] = (f16)((acc[i][j][r] + bv_) * QSCALE);
                }
            } else if (mat == 1) {
                #pragma unroll
                for (int i = 0; i < 4; ++i) {
                    const int m0 = bm * 64 + i * 16 + lg * 4;
                    #pragma unroll
                    for (int r = 0; r < 4; ++r)
                        C[(size_t)(m0 + r) * 1024 + n] = (f16)(acc[i][j][r] + bv_);
                }
            } else {
                // vT[((bb*64 + h)*16 + e)*1024 + s], h = n>>4, e = n&15
                #pragma unroll
                for (int i = 0; i < 4; ++i) {
                    const int m0 = bm * 64 + i * 16 + lg * 4;
                    const int bb = m0 >> 10, s0 = m0 & 1023;
                    f16x4 pv;
                    pv[0] = (f16)(acc[i][j][0] + bv_);
                    pv[1] = (f16)(acc[i][j][1] + bv_);
                    pv[2] = (f16)(acc[i][j][2] + bv_);
                    pv[3] = (f16)(acc[i][j][3] + bv_);
                    st4(C + ((size_t)((bb * 64 + (n >> 4)) * 16 + (n & 15))) * 1024 + s0, pv);
                }
            }
        }
    }
    gridbarrier(flags, gen, 2);

    // ================= P2: flash attention (1024 tiles over 768 blocks) ======
    {
        const f16* qlin = ws + 10485760;
        const f16* klin = ws + 12582912;
        const f16* vT   = ws + 14680064;
        f16* merged     = ws + 16777216;

        const int l5 = lane & 31, hh = lane >> 5;
        int offKa[4];
        #pragma unroll
        for (int mt = 0; mt < 4; ++mt) {
            const int r = mt * 32 + l5, g = r >> 2;
            offKa[mt] = g * 64 + (((((r & 3) * 2 + hh) + g) & 7) * 8);
        }
        const int sp = ((lane & 7) - (lane >> 3)) & 7;

        for (int v = blockIdx.x; v < 1024; v += NBLK) {
            __syncthreads();   // protect shared tile reuse across v-iterations
            const int h = v & 63, qt = (v >> 6) & 7, b = v >> 9;
            const int rowQ0 = b * 1024 + qt * 128;
            const int colh = h * 16;

            f16x8 qf = ld8(qlin + (size_t)(rowQ0 + w * 32 + l5) * 1024 + colh + hh * 8);

            const f16* kptr = klin + (size_t)(b * 1024 + w * 32 + (lane >> 3) * 4 + (sp >> 1)) * 1024
                              + colh + (sp & 1) * 8;
            const int ve = t >> 4, vk = (t & 15) * 8;
            const f16* vptr = vT + (size_t)((b * 64 + h) * 16 + ve) * 1024 + vk;
            f16* vdst0 = &sm.a.Vs[0][ve * 136 + vk];
            f16* vdst1 = &sm.a.Vs[1][ve * 136 + vk];

            float lsum = 0.f;
            f32x4 O0 = {}, O1 = {};
            f16* Pw = sm.a.Ps[w];

            f16x8 vv = ld8(vptr);
            gll16(kptr, &sm.a.Ks[0][w * 512]);
            st8(vdst0, vv);

            for (int kt = 0; kt < 8; ++kt) {
                const int cur = kt & 1;
                if (kt < 7) vv = ld8(vptr + (kt + 1) * 128);
                __syncthreads();
                if (kt < 7) {
                    gll16(kptr + (size_t)(kt + 1) * 131072, &sm.a.Ks[cur ^ 1][w * 512]);
                    st8(cur ? vdst0 : vdst1, vv);
                }

                #pragma unroll
                for (int mt = 0; mt < 4; ++mt) {
                    f16x8 ka = ld8(&sm.a.Ks[cur][offKa[mt]]);
                    f32x16 Sz = {};
                    f32x16 S = MFMA32(ka, qf, Sz);   // S^T[key][q], q = l5

                    #pragma unroll
                    for (int g = 0; g < 4; ++g) {
                        float p0 = EXP2(S[4 * g + 0]);
                        float p1 = EXP2(S[4 * g + 1]);
                        float p2 = EXP2(S[4 * g + 2]);
                        float p3 = EXP2(S[4 * g + 3]);
                        lsum += (p0 + p1) + (p2 + p3);
                        f16x4 pk;
                        pk[0] = (f16)p0; pk[1] = (f16)p1; pk[2] = (f16)p2; pk[3] = (f16)p3;
                        st4(&Pw[l5 * 40 + g * 8 + hh * 4], pk);
                    }

                    f16x8 va  = ld8(&sm.a.Vs[cur][ll * 136 + mt * 32 + lg * 8]);
                    f16x8 pb0 = ld8(&Pw[ll * 40 + lg * 8]);
                    f16x8 pb1 = ld8(&Pw[(16 + ll) * 40 + lg * 8]);
                    O0 = MFMA16(va, pb0, O0);
                    O1 = MFMA16(va, pb1, O1);
                }
            }

            lsum += __shfl_xor(lsum, 32);
            const float i0 = 1.f / __shfl(lsum, ll);
            const float i1 = 1.f / __shfl(lsum, 16 + ll);

            f16x4 o0, o1;
            o0[0]=(f16)(O0[0]*i0); o0[1]=(f16)(O0[1]*i0); o0[2]=(f16)(O0[2]*i0); o0[3]=(f16)(O0[3]*i0);
            o1[0]=(f16)(O1[0]*i1); o1[1]=(f16)(O1[1]*i1); o1[2]=(f16)(O1[2]*i1); o1[3]=(f16)(O1[3]*i1);
            const size_t q0 = rowQ0 + w * 32 + ll;
            st4(merged + q0 * 1024 + colh + lg * 4, o0);
            st4(merged + (q0 + 16) * 1024 + colh + lg * 4, o1);
        }
    }
    gridbarrier(flags, gen, 3);

    // ================= P3: output projection, 64x64 tile, dbuf, fp32 out =====
    if (blockIdx.x < 512) {
        const f16* Am  = ws + 16777216;
        const f16* Bw  = ws + 9437184;
        const int bn = blockIdx.x & 15, bm = blockIdx.x >> 4;

        f16* As = sm.o.As;
        f16* Bs = sm.o.Bs;
        const int swz = ((lane & 7) ^ (lane >> 3)) * 8;

        const f16* Ap = Am + (size_t)(bm * 64 + w * 8 + (lane >> 3)) * 1024 + swz;
        const f16* Bp = Bw + (size_t)(bn * 64 + w * 8 + (lane >> 3)) * 1024 + swz;

        f32x4 acc[4] = {};
        const int ll7 = ll & 7;

        gll16(Ap,         &As[w * 512]);
        gll16(Ap + 32768, &As[2048 + w * 512]);
        gll16(Bp,         &Bs[w * 512]);
        gll16(Bp + 32768, &Bs[2048 + w * 512]);

        #pragma unroll 2
        for (int kt = 0; kt < 16; ++kt) {
            const int cur = kt & 1;
            __syncthreads();
            if (kt < 15) {
                const f16* Ak = Ap + (kt + 1) * 64;
                const f16* Bk = Bp + (kt + 1) * 64;
                f16* Ad = &As[(cur ^ 1) * 4096 + w * 512];
                f16* Bd = &Bs[(cur ^ 1) * 4096 + w * 512];
                gll16(Ak,         Ad);
                gll16(Ak + 32768, Ad + 2048);
                gll16(Bk,         Bd);
                gll16(Bk + 32768, Bd + 2048);
            }
            const f16* Ac = &As[cur * 4096];
            const f16* Bc = &Bs[cur * 4096];
            #pragma unroll
            for (int ks = 0; ks < 2; ++ks) {
                f16x8 af[4], bf;
                #pragma unroll
                for (int i = 0; i < 4; ++i)
                    af[i] = ld8(&Ac[(i * 16 + ll) * 64 + (((ks * 4 + lg) ^ ll7) * 8)]);
                bf = ld8(&Bc[(w * 16 + ll) * 64 + (((ks * 4 + lg) ^ ll7) * 8)]);
                #pragma unroll
                for (int i = 0; i < 4; ++i)
                    acc[i] = MFMA16(af[i], bf, acc[i]);
            }
        }

        const int n = bn * 64 + w * 16 + ll;
        const float bv_ = bo[n];
        #pragma unroll
        for (int i = 0; i < 4; ++i) {
            const int m0 = bm * 64 + i * 16 + lg * 4;
            #pragma unroll
            for (int r = 0; r < 4; ++r)
                out[(size_t)(m0 + r) * 1024 + n] = acc[i][r] + bv_;
        }
    }
}

extern "C" void kernel_launch(void* const* d_in, const int* in_sizes, int n_in,
                              void* d_out, int out_size, void* d_ws, size_t ws_size,
                              hipStream_t stream) {
    (void)in_sizes; (void)n_in; (void)out_size; (void)ws_size;
    const float* Q  = (const float*)d_in[0];
    const float* K  = (const float*)d_in[1];
    const float* V  = (const float*)d_in[2];
    const float* Wq = (const float*)d_in[3];
    const float* bq = (const float*)d_in[4];
    const float* Wk = (const float*)d_in[5];
    const float* bk = (const float*)d_in[6];
    const float* Wv = (const float*)d_in[7];
    const float* bv = (const float*)d_in[8];
    const float* Wo = (const float*)d_in[9];
    const float* bo = (const float*)d_in[10];
    float* out = (float*)d_out;
    f16* ws = (f16*)d_ws;

    fused<<<NBLK, 256, 0, stream>>>(Q, K, V, Wq, bq, Wk, bk, Wv, bv, Wo, bo, ws, out);
}

// Round 8
// 154.510 us; speedup vs baseline: 2.7377x; 2.5641x over previous
//
#include <hip/hip_runtime.h>
#include <cstdint>
#include <cstddef>
#include <math.h>

typedef _Float16 f16;
typedef _Float16 f16x8 __attribute__((ext_vector_type(8)));
typedef _Float16 f16x4 __attribute__((ext_vector_type(4)));
typedef float f32x4 __attribute__((ext_vector_type(4)));
typedef float f32x16 __attribute__((ext_vector_type(16)));

#define MFMA16(A, B, C) __builtin_amdgcn_mfma_f32_16x16x32_f16((A), (B), (C), 0, 0, 0)
#define MFMA32(A, B, C) __builtin_amdgcn_mfma_f32_32x32x16_f16((A), (B), (C), 0, 0, 0)

#if __has_builtin(__builtin_amdgcn_exp2f)
#define EXP2(x) __builtin_amdgcn_exp2f(x)
#else
#define EXP2(x) exp2f(x)
#endif

__device__ __forceinline__ f16x8 ld8(const f16* p) { return *(const f16x8*)p; }
__device__ __forceinline__ void st8(f16* p, f16x8 v) { *(f16x8*)p = v; }
__device__ __forceinline__ void st4(f16* p, f16x4 v) { *(f16x4*)p = v; }

__device__ __forceinline__ void gll16(const f16* g, f16* l) {
    __builtin_amdgcn_global_load_lds(
        (__attribute__((address_space(1))) void*)(uintptr_t)g,
        (__attribute__((address_space(3))) void*)(unsigned)(uintptr_t)l,
        16, 0, 0);
}

// ---------------- K0: fp32 -> f16 cast of Q,K,V,Wq,Wk,Wv,Wo ----------------
// ws f16 layout (elements):
//   Qc 0, Kc 2097152, Vc 4194304, Wqc 6291456, Wkc 7340032, Wvc 8388608,
//   Woc 9437184, qlin 10485760, klin 12582912, vT 14680064, merged 16777216
__global__ __launch_bounds__(256) void cast_all(
    const float* __restrict__ Q, const float* __restrict__ K, const float* __restrict__ V,
    const float* __restrict__ Wq, const float* __restrict__ Wk, const float* __restrict__ Wv,
    const float* __restrict__ Wo, f16* __restrict__ dst)
{
    size_t e = ((size_t)blockIdx.x * 256 + threadIdx.x) * 8;
    const float* s; size_t r;
    if (e < 2097152)      { s = Q;  r = e; }
    else if (e < 4194304) { s = K;  r = e - 2097152; }
    else if (e < 6291456) { s = V;  r = e - 4194304; }
    else if (e < 7340032) { s = Wq; r = e - 6291456; }
    else if (e < 8388608) { s = Wk; r = e - 7340032; }
    else if (e < 9437184) { s = Wv; r = e - 8388608; }
    else                  { s = Wo; r = e - 9437184; }
    float4 a = *(const float4*)(s + r);
    float4 b = *(const float4*)(s + r + 4);
    f16x8 o;
    o[0]=(f16)a.x; o[1]=(f16)a.y; o[2]=(f16)a.z; o[3]=(f16)a.w;
    o[4]=(f16)b.x; o[5]=(f16)b.y; o[6]=(f16)b.z; o[7]=(f16)b.w;
    st8(dst + e, o);
}

// ---------------- K1: fused QKV GEMM, 64x128 tile, BK=64, dbuf, MFMA32 ------
// grid (24,32): bx = mat*8 + bn(128 n-cols), by = bm(64 m-rows). 4 waves, each
// 64x32 via 2x MFMA32 per k-step. r3 gll16 swizzled staging; r4 epilogue.
// mat 0 -> qlin pre-scaled by log2e/32; mat 1 -> klin; mat 2 -> vT transposed.
__global__ __launch_bounds__(256) void qkv_gemm(
    const f16* __restrict__ ws, const float* __restrict__ bq,
    const float* __restrict__ bk, const float* __restrict__ bv,
    f16* __restrict__ outbase)
{
    const int bx = blockIdx.x, bm = blockIdx.y;
    const int mat = bx >> 3, bn = bx & 7;
    const f16* A  = ws + (size_t)mat * 2097152;
    const f16* Bw = ws + 6291456 + (size_t)mat * 1048576;
    const float* bias = (mat == 0) ? bq : (mat == 1) ? bk : bv;
    f16* C = outbase + (size_t)mat * 2097152;

    __shared__ f16 As[2 * 4096];   // [buf][64 rows][64 cols], 16B chunks swizzled
    __shared__ f16 Bs[2 * 8192];   // [buf][128 rows][64 cols]
    const int t = threadIdx.x;
    const int w = t >> 6, lane = t & 63, l5 = lane & 31, hh = lane >> 5;
    const int swz = ((lane & 7) ^ (lane >> 3)) * 8;   // swizzled source col
    const int l7 = l5 & 7;

    const f16* Ap = A  + (size_t)(bm * 64  + w * 8 + (lane >> 3)) * 1024 + swz;
    const f16* Bp = Bw + (size_t)(bn * 128 + w * 8 + (lane >> 3)) * 1024 + swz;

    f32x16 acc[2] = {};

    gll16(Ap,         &As[w * 512]);
    gll16(Ap + 32768, &As[2048 + w * 512]);
    #pragma unroll
    for (int q = 0; q < 4; ++q)
        gll16(Bp + q * 32768, &Bs[q * 2048 + w * 512]);

    #pragma unroll 2
    for (int kt = 0; kt < 16; ++kt) {
        const int cur = kt & 1;
        __syncthreads();
        if (kt < 15) {
            const f16* Ak = Ap + (kt + 1) * 64;
            const f16* Bk = Bp + (kt + 1) * 64;
            f16* Ad = &As[(cur ^ 1) * 4096 + w * 512];
            f16* Bd = &Bs[(cur ^ 1) * 8192 + w * 512];
            gll16(Ak,         Ad);
            gll16(Ak + 32768, Ad + 2048);
            #pragma unroll
            for (int q = 0; q < 4; ++q)
                gll16(Bk + q * 32768, Bd + q * 2048);
        }
        const f16* Ac = &As[cur * 4096];
        const f16* Bc = &Bs[cur * 8192];
        #pragma unroll
        for (int ks = 0; ks < 4; ++ks) {
            const int c = ks * 2 + hh;                  // 16B chunk index in row
            f16x8 bfr = ld8(&Bc[(w * 32 + l5) * 64 + ((c ^ l7) * 8)]);
            f16x8 af0 = ld8(&Ac[ l5       * 64 + ((c ^ l7) * 8)]);
            f16x8 af1 = ld8(&Ac[(32 + l5) * 64 + ((c ^ l7) * 8)]);
            acc[0] = MFMA32(af0, bfr, acc[0]);
            acc[1] = MFMA32(af1, bfr, acc[1]);
        }
    }

    const float qscale = 0.04508422002778009f;   // log2(e)/32 folded into qlin
    const int n = bn * 128 + w * 32 + l5;        // lane owns ONE output column
    const float bv_ = bias[n];
    if (mat == 0) {
        #pragma unroll
        for (int i = 0; i < 2; ++i)
            #pragma unroll
            for (int r = 0; r < 16; ++r) {
                const int m = bm * 64 + i * 32 + (r & 3) + 8 * (r >> 2) + 4 * hh;
                C[(size_t)m * 1024 + n] = (f16)((acc[i][r] + bv_) * qscale);
            }
    } else if (mat == 1) {
        #pragma unroll
        for (int i = 0; i < 2; ++i)
            #pragma unroll
            for (int r = 0; r < 16; ++r) {
                const int m = bm * 64 + i * 32 + (r & 3) + 8 * (r >> 2) + 4 * hh;
                C[(size_t)m * 1024 + n] = (f16)(acc[i][r] + bv_);
            }
    } else {
        // vT[((bb*64 + h)*16 + e)*1024 + s], h = n>>4, e = n&15
        const int hN = n >> 4, eN = n & 15;
        #pragma unroll
        for (int i = 0; i < 2; ++i)
            #pragma unroll
            for (int g = 0; g < 4; ++g) {
                const int m0 = bm * 64 + i * 32 + 8 * g + 4 * hh;  // 4 consecutive s
                const int bb = m0 >> 10, s0 = m0 & 1023;
                f16x4 pv;
                pv[0] = (f16)(acc[i][4 * g + 0] + bv_);
                pv[1] = (f16)(acc[i][4 * g + 1] + bv_);
                pv[2] = (f16)(acc[i][4 * g + 2] + bv_);
                pv[3] = (f16)(acc[i][4 * g + 3] + bv_);
                st4(C + ((size_t)((bb * 64 + hN) * 16 + eN)) * 1024 + s0, pv);
            }
    }
}

// ---------------- K2: flash attention, 64 heads of dim 16 (r3, unchanged) ---
__global__ __launch_bounds__(256, 4) void attn(
    const f16* __restrict__ qlin, const f16* __restrict__ klin,
    const f16* __restrict__ vT, f16* __restrict__ merged)
{
    __shared__ f16 Ks[2][2048];      // [buf][key 128][e 16], swizzled chunks
    __shared__ f16 Vs[2][2176];      // [buf][e 16][key 128], pitch 136
    __shared__ f16 Ps[4][1280];      // per-wave P [q 32][key 32], pitch 40

    const int t = threadIdx.x;
    const int w = t >> 6, lane = t & 63;
    const int l5 = lane & 31, hh = lane >> 5, lg = (lane >> 4) & 3, ll = lane & 15;
    const int h = blockIdx.x, qt = blockIdx.y, b = blockIdx.z;

    const int rowQ0 = b * 1024 + qt * 128;
    const int colh = h * 16;

    f16x8 qf = ld8(qlin + (size_t)(rowQ0 + w * 32 + l5) * 1024 + colh + hh * 8);

    const int sp = ((lane & 7) - (lane >> 3)) & 7;
    const f16* kptr = klin + (size_t)(b * 1024 + w * 32 + (lane >> 3) * 4 + (sp >> 1)) * 1024
                      + colh + (sp & 1) * 8;
    const int ve = t >> 4, vk = (t & 15) * 8;
    const f16* vptr = vT + (size_t)((b * 64 + h) * 16 + ve) * 1024 + vk;
    f16* vdst0 = &Vs[0][ve * 136 + vk];
    f16* vdst1 = &Vs[1][ve * 136 + vk];

    int offKa[4];
    #pragma unroll
    for (int mt = 0; mt < 4; ++mt) {
        const int r = mt * 32 + l5, g = r >> 2;
        offKa[mt] = g * 64 + (((((r & 3) * 2 + hh) + g) & 7) * 8);
    }

    float lsum = 0.f;
    f32x4 O0 = {}, O1 = {};
    f16* Pw = Ps[w];

    f16x8 vv = ld8(vptr);
    gll16(kptr, &Ks[0][w * 512]);
    st8(vdst0, vv);

    for (int kt = 0; kt < 8; ++kt) {
        const int cur = kt & 1;
        if (kt < 7) vv = ld8(vptr + (kt + 1) * 128);
        __syncthreads();
        if (kt < 7) {
            gll16(kptr + (size_t)(kt + 1) * 131072, &Ks[cur ^ 1][w * 512]);
            st8(cur ? vdst0 : vdst1, vv);
        }

        #pragma unroll
        for (int mt = 0; mt < 4; ++mt) {
            f16x8 ka = ld8(&Ks[cur][offKa[mt]]);
            f32x16 Sz = {};
            f32x16 S = MFMA32(ka, qf, Sz);   // S^T[key][q], q = l5

            #pragma unroll
            for (int g = 0; g < 4; ++g) {
                float p0 = EXP2(S[4 * g + 0]);
                float p1 = EXP2(S[4 * g + 1]);
                float p2 = EXP2(S[4 * g + 2]);
                float p3 = EXP2(S[4 * g + 3]);
                lsum += (p0 + p1) + (p2 + p3);
                f16x4 pk;
                pk[0] = (f16)p0; pk[1] = (f16)p1; pk[2] = (f16)p2; pk[3] = (f16)p3;
                st4(&Pw[l5 * 40 + g * 8 + hh * 4], pk);
            }

            f16x8 va  = ld8(&Vs[cur][ll * 136 + mt * 32 + lg * 8]);
            f16x8 pb0 = ld8(&Pw[ll * 40 + lg * 8]);
            f16x8 pb1 = ld8(&Pw[(16 + ll) * 40 + lg * 8]);
            O0 = MFMA16(va, pb0, O0);
            O1 = MFMA16(va, pb1, O1);
        }
    }

    lsum += __shfl_xor(lsum, 32);
    const float i0 = 1.f / __shfl(lsum, ll);
    const float i1 = 1.f / __shfl(lsum, 16 + ll);

    f16x4 o0, o1;
    o0[0]=(f16)(O0[0]*i0); o0[1]=(f16)(O0[1]*i0); o0[2]=(f16)(O0[2]*i0); o0[3]=(f16)(O0[3]*i0);
    o1[0]=(f16)(O1[0]*i1); o1[1]=(f16)(O1[1]*i1); o1[2]=(f16)(O1[2]*i1); o1[3]=(f16)(O1[3]*i1);
    const size_t q0 = rowQ0 + w * 32 + ll;
    st4(merged + q0 * 1024 + colh + lg * 4, o0);
    st4(merged + (q0 + 16) * 1024 + colh + lg * 4, o1);
}

// ---------------- K3: output projection, 64x64, BK=64, dbuf, MFMA32, fp32 out
__global__ __launch_bounds__(256) void o_gemm(
    const f16* __restrict__ A, const f16* __restrict__ Bw,
    const float* __restrict__ bias, float* __restrict__ Cf)
{
    const int bn = blockIdx.x, bm = blockIdx.y;   // grid (16, 32)
    __shared__ f16 As[2 * 4096];
    __shared__ f16 Bs[2 * 4096];
    const int t = threadIdx.x;
    const int w = t >> 6, lane = t & 63, l5 = lane & 31, hh = lane >> 5;
    const int wr = w >> 1, wc = w & 1;            // 2x2 waves cover 64x64
    const int swz = ((lane & 7) ^ (lane >> 3)) * 8;
    const int l7 = l5 & 7;

    const f16* Ap = A  + (size_t)(bm * 64 + w * 8 + (lane >> 3)) * 1024 + swz;
    const f16* Bp = Bw + (size_t)(bn * 64 + w * 8 + (lane >> 3)) * 1024 + swz;

    f32x16 acc = {};

    gll16(Ap,         &As[w * 512]);
    gll16(Ap + 32768, &As[2048 + w * 512]);
    gll16(Bp,         &Bs[w * 512]);
    gll16(Bp + 32768, &Bs[2048 + w * 512]);

    #pragma unroll 2
    for (int kt = 0; kt < 16; ++kt) {
        const int cur = kt & 1;
        __syncthreads();
        if (kt < 15) {
            const f16* Ak = Ap + (kt + 1) * 64;
            const f16* Bk = Bp + (kt + 1) * 64;
            f16* Ad = &As[(cur ^ 1) * 4096 + w * 512];
            f16* Bd = &Bs[(cur ^ 1) * 4096 + w * 512];
            gll16(Ak,         Ad);
            gll16(Ak + 32768, Ad + 2048);
            gll16(Bk,         Bd);
            gll16(Bk + 32768, Bd + 2048);
        }
        const f16* Ac = &As[cur * 4096];
        const f16* Bc = &Bs[cur * 4096];
        #pragma unroll
        for (int ks = 0; ks < 4; ++ks) {
            const int c = ks * 2 + hh;
            f16x8 af = ld8(&Ac[(wr * 32 + l5) * 64 + ((c ^ l7) * 8)]);
            f16x8 bf = ld8(&Bc[(wc * 32 + l5) * 64 + ((c ^ l7) * 8)]);
            acc = MFMA32(af, bf, acc);
        }
    }

    const int n = bn * 64 + wc * 32 + l5;
    const float bv_ = bias[n];
    #pragma unroll
    for (int r = 0; r < 16; ++r) {
        const int m = bm * 64 + wr * 32 + (r & 3) + 8 * (r >> 2) + 4 * hh;
        Cf[(size_t)m * 1024 + n] = acc[r] + bv_;
    }
}

extern "C" void kernel_launch(void* const* d_in, const int* in_sizes, int n_in,
                              void* d_out, int out_size, void* d_ws, size_t ws_size,
                              hipStream_t stream) {
    (void)in_sizes; (void)n_in; (void)out_size; (void)ws_size;
    const float* Q  = (const float*)d_in[0];
    const float* K  = (const float*)d_in[1];
    const float* V  = (const float*)d_in[2];
    const float* Wq = (const float*)d_in[3];
    const float* bq = (const float*)d_in[4];
    const float* Wk = (const float*)d_in[5];
    const float* bk = (const float*)d_in[6];
    const float* Wv = (const float*)d_in[7];
    const float* bv = (const float*)d_in[8];
    const float* Wo = (const float*)d_in[9];
    const float* bo = (const float*)d_in[10];
    float* out = (float*)d_out;

    f16* ws = (f16*)d_ws;
    f16* qlin   = ws + 10485760;
    f16* klin   = ws + 12582912;
    f16* vT     = ws + 14680064;
    f16* merged = ws + 16777216;
    f16* Woc    = ws + 9437184;

    cast_all<<<5120, 256, 0, stream>>>(Q, K, V, Wq, Wk, Wv, Wo, ws);
    qkv_gemm<<<dim3(24, 32), 256, 0, stream>>>(ws, bq, bk, bv, qlin);
    attn<<<dim3(64, 8, 2), 256, 0, stream>>>(qlin, klin, vT, merged);
    o_gemm<<<dim3(16, 32), 256, 0, stream>>>(merged, Woc, bo, out);
}